// Round 3
// baseline (54.247 us; speedup 1.0000x reference)
//
#include <hip/hip_runtime.h>
#include <hip/hip_bf16.h>
#include <math.h>

#define T_DIM 32
#define B_DIM 128
#define D_DIM 512
#define M_DIM 1024

constexpr float DT = 0.1875f;            // 3.0 / 16

typedef __attribute__((ext_vector_type(8))) short bf16x8;   // 8 bf16 = 4 VGPR
typedef __attribute__((ext_vector_type(4))) float f32x4;    // MFMA acc

__device__ __forceinline__ ushort f2bf(float f) {           // RNE fp32->bf16
    unsigned u = __float_as_uint(f);
    u += 0x7FFFu + ((u >> 16) & 1u);
    return (ushort)(u >> 16);
}

// v_sin_f32/v_cos_f32 take input in REVOLUTIONS (ISA: D=sin(S0*2pi)); reduce with floor.
__device__ __forceinline__ void fast_sincos(float theta, float& s, float& c) {
    constexpr float INV_2PI = 0.15915494309189535f;
    float r = theta * INV_2PI;
    r -= floorf(r);
    s = __builtin_amdgcn_sinf(r);
    c = __builtin_amdgcn_cosf(r);
}

// ---------- K1: column inverse norms of A (1024 cols) ----------
__global__ __launch_bounds__(256) void colnorm_kernel(const float* __restrict__ A,
                                                      float* __restrict__ invn) {
    __shared__ float red[256];
    const int mB = blockIdx.x * 16;            // 64 blocks
    const int mo = threadIdx.x & 15;
    const int dg = threadIdx.x >> 4;           // 16 d-groups of 32
    float ss = 0.0f;
#pragma unroll 4
    for (int i = 0; i < 32; ++i) {
        float v = A[(size_t)(dg * 32 + i) * M_DIM + mB + mo];
        ss = fmaf(v, v, ss);
    }
    red[threadIdx.x] = ss;
    __syncthreads();
    for (int s = 128; s >= 16; s >>= 1) {
        if (threadIdx.x < s) red[threadIdx.x] += red[threadIdx.x + s];
        __syncthreads();
    }
    if (threadIdx.x < 16)
        invn[mB + mo] = 1.0f / fmaxf(sqrtf(red[threadIdx.x]), 1e-12f);
}

// ---------- K2: z fp32 -> bf16 (same layout) ----------
__global__ __launch_bounds__(256) void zconv_kernel(const float* __restrict__ z,
                                                    ushort* __restrict__ zb) {
    const size_t i = ((size_t)blockIdx.x * 256 + threadIdx.x) * 8;   // 1024 blocks, exact
    const float4 a = *reinterpret_cast<const float4*>(&z[i]);
    const float4 b = *reinterpret_cast<const float4*>(&z[i + 4]);
    uint4 p;
    p.x = (unsigned)f2bf(a.x) | ((unsigned)f2bf(a.y) << 16);
    p.y = (unsigned)f2bf(a.z) | ((unsigned)f2bf(a.w) << 16);
    p.z = (unsigned)f2bf(b.x) | ((unsigned)f2bf(b.y) << 16);
    p.w = (unsigned)f2bf(b.z) | ((unsigned)f2bf(b.w) << 16);
    *reinterpret_cast<uint4*>(&zb[i]) = p;
}

// ---------- K3: Ant[m][d] = A[d][m] * invn[m], bf16 (LDS tile transpose) ----------
__global__ __launch_bounds__(256) void atrans_kernel(const float* __restrict__ A,
                                                     const float* __restrict__ invn,
                                                     ushort* __restrict__ ant) {
    __shared__ float tile[64][65];
    const int dB = blockIdx.x * 64;            // 8
    const int mB = blockIdx.y * 64;            // 16
#pragma unroll
    for (int it = 0; it < 4; ++it) {
        const int r = it * 16 + (threadIdx.x >> 4);
        const int c = (threadIdx.x & 15) * 4;
        const float4 v = *reinterpret_cast<const float4*>(&A[(size_t)(dB + r) * M_DIM + mB + c]);
        tile[r][c] = v.x; tile[r][c + 1] = v.y; tile[r][c + 2] = v.z; tile[r][c + 3] = v.w;
    }
    __syncthreads();
#pragma unroll
    for (int it = 0; it < 2; ++it) {
        const int ci = it * 256 + threadIdx.x;
        const int orow = ci >> 3;              // 0..63 (m-local)
        const int oc = (ci & 7) * 8;           // 0..56 (d-local)
        const float sc = invn[mB + orow];
        uint4 p;
        p.x = (unsigned)f2bf(tile[oc + 0][orow] * sc) | ((unsigned)f2bf(tile[oc + 1][orow] * sc) << 16);
        p.y = (unsigned)f2bf(tile[oc + 2][orow] * sc) | ((unsigned)f2bf(tile[oc + 3][orow] * sc) << 16);
        p.z = (unsigned)f2bf(tile[oc + 4][orow] * sc) | ((unsigned)f2bf(tile[oc + 5][orow] * sc) << 16);
        p.w = (unsigned)f2bf(tile[oc + 6][orow] * sc) | ((unsigned)f2bf(tile[oc + 7][orow] * sc) << 16);
        *reinterpret_cast<uint4*>(&ant[(size_t)(mB + orow) * D_DIM + dB + oc]) = p;
    }
}

// ---------- K4: fused bf16-MFMA GEMM + CF statistic ----------
// block: 256 thr (4 waves, 2x2), tile 128 rows (all b of one t) x 64 cols; K=512, BK=64.
__global__ __launch_bounds__(256) void fused_kernel(const ushort* __restrict__ zb,
                                                    const ushort* __restrict__ ant,
                                                    float* __restrict__ partials) {
    __shared__ __align__(16) ushort As[128][72];    // +16B pad per row
    __shared__ __align__(16) ushort Bs[64][72];
    __shared__ float wred[2][32][32];               // [wc][col][k | 16+k]
    __shared__ float bred[2];

    const int tid  = threadIdx.x;
    const int mB   = blockIdx.x * 64;               // 16 m-blocks (fast: share zb slice in L2)
    const int t    = blockIdx.y;                    // 0..31
    const int wave = tid >> 6;
    const int lane = tid & 63;
    const int wr   = wave >> 1;                     // row half
    const int wc   = wave & 1;                      // col half
    const int l15  = lane & 15;
    const int lhi  = lane >> 4;

    const ushort* zrow = zb + (size_t)t * B_DIM * D_DIM;

    // load index mappings (uniform per thread)
    const int ar0 = tid >> 3;            // A rows: tid/8 + 32*q
    const int ac  = (tid & 7) * 8;       // A col within BK
    const int br0 = tid >> 3;            // B rows: tid/8 + 32*q (q<2)
    const int bc  = (tid & 7) * 8;

    f32x4 acc[4][2];
#pragma unroll
    for (int fm = 0; fm < 4; ++fm)
#pragma unroll
        for (int fn = 0; fn < 2; ++fn) acc[fm][fn] = (f32x4)(0.0f);

    uint4 aReg[4], bReg[2];
#pragma unroll
    for (int q = 0; q < 4; ++q)
        aReg[q] = *reinterpret_cast<const uint4*>(&zrow[(size_t)(ar0 + 32 * q) * D_DIM + ac]);
#pragma unroll
    for (int q = 0; q < 2; ++q)
        bReg[q] = *reinterpret_cast<const uint4*>(&ant[(size_t)(mB + br0 + 32 * q) * D_DIM + bc]);

#pragma unroll
    for (int it = 0; it < 8; ++it) {
        __syncthreads();                            // prior MFMA reads done
#pragma unroll
        for (int q = 0; q < 4; ++q)
            *reinterpret_cast<uint4*>(&As[ar0 + 32 * q][ac]) = aReg[q];
#pragma unroll
        for (int q = 0; q < 2; ++q)
            *reinterpret_cast<uint4*>(&Bs[br0 + 32 * q][bc]) = bReg[q];
        __syncthreads();

        if (it < 7) {                               // prefetch next K-tile (issue-early)
            const int k0 = (it + 1) * 64;
#pragma unroll
            for (int q = 0; q < 4; ++q)
                aReg[q] = *reinterpret_cast<const uint4*>(&zrow[(size_t)(ar0 + 32 * q) * D_DIM + k0 + ac]);
#pragma unroll
            for (int q = 0; q < 2; ++q)
                bReg[q] = *reinterpret_cast<const uint4*>(&ant[(size_t)(mB + br0 + 32 * q) * D_DIM + k0 + bc]);
        }

#pragma unroll
        for (int ks = 0; ks < 2; ++ks) {
            bf16x8 af[4], bf[2];
#pragma unroll
            for (int fm = 0; fm < 4; ++fm)
                af[fm] = *reinterpret_cast<const bf16x8*>(&As[wr * 64 + fm * 16 + l15][ks * 32 + lhi * 8]);
#pragma unroll
            for (int fn = 0; fn < 2; ++fn)
                bf[fn] = *reinterpret_cast<const bf16x8*>(&Bs[wc * 32 + fn * 16 + l15][ks * 32 + lhi * 8]);
#pragma unroll
            for (int fm = 0; fm < 4; ++fm)
#pragma unroll
                for (int fn = 0; fn < 2; ++fn)
                    acc[fm][fn] = __builtin_amdgcn_mfma_f32_16x16x32_bf16(af[fm], bf[fn], acc[fm][fn], 0, 0, 0);
        }
    }

    // ---- per-lane CF accumulation (Chebyshev recurrence over 16 knots, float2-packed) ----
    float2 accCS[2][16];
#pragma unroll
    for (int fn = 0; fn < 2; ++fn)
#pragma unroll
        for (int k = 0; k < 16; ++k) accCS[fn][k] = make_float2(0.0f, 0.0f);

#pragma unroll
    for (int fn = 0; fn < 2; ++fn)
#pragma unroll
        for (int fm = 0; fm < 4; ++fm)
#pragma unroll
            for (int r = 0; r < 4; ++r) {
                float s1, c1;
                fast_sincos(acc[fm][fn][r] * DT, s1, c1);
                const float c2 = 2.0f * c1;
                float2 prev = make_float2(1.0f, 0.0f);
                float2 cur  = make_float2(c1, s1);
                accCS[fn][0].x += cur.x; accCS[fn][0].y += cur.y;
#pragma unroll
                for (int k = 1; k < 16; ++k) {
                    float2 nxt;
                    nxt.x = fmaf(c2, cur.x, -prev.x);
                    nxt.y = fmaf(c2, cur.y, -prev.y);
                    prev = cur; cur = nxt;
                    accCS[fn][k].x += cur.x; accCS[fn][k].y += cur.y;
                }
            }

    // reduce over the wave's 64 rows (lane>>4 groups)
#pragma unroll
    for (int fn = 0; fn < 2; ++fn)
#pragma unroll
        for (int k = 0; k < 16; ++k) {
            accCS[fn][k].x += __shfl_xor(accCS[fn][k].x, 16);
            accCS[fn][k].x += __shfl_xor(accCS[fn][k].x, 32);
            accCS[fn][k].y += __shfl_xor(accCS[fn][k].y, 16);
            accCS[fn][k].y += __shfl_xor(accCS[fn][k].y, 32);
        }

    if (wr == 0 && lane < 16) {
#pragma unroll
        for (int fn = 0; fn < 2; ++fn)
#pragma unroll
            for (int k = 0; k < 16; ++k) {
                wred[wc][fn * 16 + l15][k]      = accCS[fn][k].x;
                wred[wc][fn * 16 + l15][16 + k] = accCS[fn][k].y;
            }
    }
    __syncthreads();

    if (wr == 1) {
        const float invB = 1.0f / 128.0f;
        float s = 0.0f;
#pragma unroll
        for (int fn = 0; fn < 2; ++fn) {
#pragma unroll
            for (int kk = 1; kk <= 16; ++kk) {
                const float tk = DT * (float)kk;
                const float g  = __expf(-0.5f * tk * tk);
                const float w  = ((kk == 16) ? DT : 2.0f * DT) * g;
                const float totC = wred[wc][fn * 16 + l15][kk - 1]      + accCS[fn][kk - 1].x;
                const float totS = wred[wc][fn * 16 + l15][16 + kk - 1] + accCS[fn][kk - 1].y;
                const float cm = fmaf(totC, invB, -g);
                const float sm = totS * invB;
                s = fmaf(w, fmaf(cm, cm, sm * sm), s);
            }
        }
        // butterfly over all 64 lanes: each col counted 4x
#pragma unroll
        for (int m = 1; m < 64; m <<= 1) s += __shfl_xor(s, m);
        if (lane == 0) bred[wc] = s;
    }
    __syncthreads();
    if (tid == 0)
        partials[blockIdx.y * 16 + blockIdx.x] = (bred[0] + bred[1]) * 0.25f * 128.0f;
}

// ---------- K5: final reduce of 512 partials ----------
__global__ __launch_bounds__(256) void finalize_kernel(const float* __restrict__ partials,
                                                       float* __restrict__ out) {
    __shared__ float red[256];
    const int tid = threadIdx.x;
    red[tid] = partials[tid] + partials[tid + 256];
    __syncthreads();
    for (int s = 128; s > 0; s >>= 1) {
        if (tid < s) red[tid] += red[tid + s];
        __syncthreads();
    }
    if (tid == 0) out[0] = red[0] * (1.0f / (float)(T_DIM * M_DIM));
}

extern "C" void kernel_launch(void* const* d_in, const int* in_sizes, int n_in,
                              void* d_out, int out_size, void* d_ws, size_t ws_size,
                              hipStream_t stream) {
    const float* z = (const float*)d_in[0];   // (32,128,512)
    const float* A = (const float*)d_in[1];   // (512,1024)
    float* out = (float*)d_out;

    float*  invn     = (float*)d_ws;                                    // 4 KB
    float*  partials = invn + 1024;                                     // 2 KB
    ushort* zb  = (ushort*)((char*)d_ws + 8192);                        // 4 MB
    ushort* ant = (ushort*)((char*)d_ws + 8192 + (size_t)T_DIM * B_DIM * D_DIM * 2); // 1 MB

    colnorm_kernel<<<64, 256, 0, stream>>>(A, invn);
    zconv_kernel<<<1024, 256, 0, stream>>>(z, zb);
    atrans_kernel<<<dim3(8, 16), 256, 0, stream>>>(A, invn, ant);

    fused_kernel<<<dim3(M_DIM / 64, T_DIM), 256, 0, stream>>>(zb, ant, partials);

    finalize_kernel<<<1, 256, 0, stream>>>(partials, out);
}